// Round 1
// baseline (604.158 us; speedup 1.0000x reference)
//
#include <hip/hip_runtime.h>
#include <stdint.h>

typedef __attribute__((ext_vector_type(8))) short short8;   // 8 x bf16 (4 VGPRs)
typedef __attribute__((ext_vector_type(4))) float f32x4;
typedef __attribute__((ext_vector_type(4))) unsigned short u16x4;
typedef unsigned short bf16_t;

__device__ __forceinline__ bf16_t f2bf(float f) {
  union { float f; uint32_t u; } x; x.f = f;
  uint32_t r = x.u + 0x7fffu + ((x.u >> 16) & 1u);   // RNE
  return (bf16_t)(r >> 16);
}

// ---------------- fp32 -> bf16 convert (vectorized, memory-bound) -------------
__global__ void convert_f32_bf16(const float* __restrict__ src,
                                 bf16_t* __restrict__ dst, int n4) {
  int i = blockIdx.x * 256 + threadIdx.x;
  if (i >= n4) return;
  f32x4 v = *(const f32x4*)(src + (size_t)i * 4);
  u16x4 o;
  o[0] = f2bf(v[0]); o[1] = f2bf(v[1]); o[2] = f2bf(v[2]); o[3] = f2bf(v[3]);
  *(u16x4*)(dst + (size_t)i * 4) = o;
}

// ---------------- NT GEMM: C[M,N] = A[M,K] * B[N,K]^T + bias[N] ---------------
// STORE: 0 = fp32 out, 1 = bf16 out, 2 = bf16 transposed out (out[n*M+m])
// 128x128 tile, 256 threads (4 waves, each 64x64 = 4x4 MFMA tiles), BK=32.
template <int STORE>
__global__ __launch_bounds__(256) void gemm_nt(
    const bf16_t* __restrict__ A, const bf16_t* __restrict__ B,
    const float* __restrict__ bias, void* __restrict__ Cout,
    int M, int N, int K) {
  __shared__ __align__(16) bf16_t As[128 * 32];
  __shared__ __align__(16) bf16_t Bs[128 * 32];
  const int tid = threadIdx.x;
  const int wv = tid >> 6, lane = tid & 63, quad = lane >> 4, l16 = lane & 15;
  const int m0 = blockIdx.y * 128, n0 = blockIdx.x * 128;
  const int m_off = (wv & 1) * 64, n_off = (wv >> 1) * 64;

  f32x4 acc[4][4];
  const f32x4 zf = {0.f, 0.f, 0.f, 0.f};
#pragma unroll
  for (int mi = 0; mi < 4; ++mi)
#pragma unroll
    for (int ni = 0; ni < 4; ++ni) acc[mi][ni] = zf;

  for (int k0 = 0; k0 < K; k0 += 32) {
    // stage 128x32 bf16 tiles of A and B: 512 16B-chunks each, 2 per thread
#pragma unroll
    for (int j = 0; j < 2; ++j) {
      int c = tid + j * 256;
      int row = c >> 2, col = (c & 3) * 8;
      *(f32x4*)(&As[row * 32 + col]) =
          *(const f32x4*)(&A[(size_t)(m0 + row) * K + k0 + col]);
      *(f32x4*)(&Bs[row * 32 + col]) =
          *(const f32x4*)(&B[(size_t)(n0 + row) * K + k0 + col]);
    }
    __syncthreads();
    short8 af[4], bf[4];
#pragma unroll
    for (int mi = 0; mi < 4; ++mi)
      af[mi] = *(const short8*)(&As[(m_off + mi * 16 + l16) * 32 + quad * 8]);
#pragma unroll
    for (int ni = 0; ni < 4; ++ni)
      bf[ni] = *(const short8*)(&Bs[(n_off + ni * 16 + l16) * 32 + quad * 8]);
#pragma unroll
    for (int mi = 0; mi < 4; ++mi)
#pragma unroll
      for (int ni = 0; ni < 4; ++ni)
        acc[mi][ni] = __builtin_amdgcn_mfma_f32_16x16x32_bf16(
            af[mi], bf[ni], acc[mi][ni], 0, 0, 0);
    __syncthreads();
  }

  // epilogue: C/D layout col = lane&15, row = quad*4 + reg  [m89/m91 verified]
#pragma unroll
  for (int mi = 0; mi < 4; ++mi) {
#pragma unroll
    for (int ni = 0; ni < 4; ++ni) {
      int n = n0 + n_off + ni * 16 + l16;
      int mbase = m0 + m_off + mi * 16 + quad * 4;
      float bv = bias[n];
#pragma unroll
      for (int r = 0; r < 4; ++r) {
        float v = acc[mi][ni][r] + bv;
        int m = mbase + r;
        if (STORE == 0) ((float*)Cout)[(size_t)m * N + n] = v;
        if (STORE == 1) ((bf16_t*)Cout)[(size_t)m * N + n] = f2bf(v);
        if (STORE == 2) ((bf16_t*)Cout)[(size_t)n * M + m] = f2bf(v);
      }
    }
  }
}

// ---------------- RoPE + bf16 cast (Q pre-scaled by 1/sqrt(128)) --------------
// grid covers 2048 positions * (16 Q heads + 4 KV heads) * 64 pairs
__global__ void rope_qk(const float* __restrict__ Qf, const float* __restrict__ Kf,
                        bf16_t* __restrict__ Qr, bf16_t* __restrict__ Kr) {
  int idx = blockIdx.x * 256 + threadIdx.x;
  int i = idx & 63;
  int rest = idx >> 6;
  int head = rest % 20;
  int s = rest / 20;
  // base_adj == 1 (seq_eff == MAX_LEN), so plain theta=10000
  float inv_freq = powf(10000.0f, -(float)i * (1.0f / 64.0f));
  float ang = (float)s * inv_freq;
  float c = cosf(ang), sn = sinf(ang);
  if (head < 16) {
    const float scale = 0.08838834764831845f;  // 1/sqrt(128)
    size_t base = (size_t)s * 2048 + head * 128 + i;
    float x1 = Qf[base], x2 = Qf[base + 64];
    Qr[base] = f2bf((x1 * c - x2 * sn) * scale);
    Qr[base + 64] = f2bf((x2 * c + x1 * sn) * scale);
  } else {
    size_t base = (size_t)s * 512 + (head - 16) * 128 + i;
    float x1 = Kf[base], x2 = Kf[base + 64];
    Kr[base] = f2bf(x1 * c - x2 * sn);
    Kr[base + 64] = f2bf(x2 * c + x1 * sn);
  }
}

// ---------------- causal GQA flash attention ---------------------------------
// grid (16 heads, 32 q-tiles of 64); 4 waves/block, each wave owns 16 q rows.
// Qr pre-scaled. Kr row-major (S,512). Vt transposed (512,S). Out bf16 (S,2048).
__global__ __launch_bounds__(256) void attn_fwd(
    const bf16_t* __restrict__ Qr, const bf16_t* __restrict__ Kr,
    const bf16_t* __restrict__ Vt, bf16_t* __restrict__ Oo) {
  const int h = blockIdx.x;
  const int qt = blockIdx.y;
  const int tid = threadIdx.x;
  const int wv = tid >> 6, lane = tid & 63, quad = lane >> 4, l16 = lane & 15;
  const int q_base = qt * 64 + wv * 16;
  const int hkv = h >> 2;

  __shared__ __align__(16) bf16_t plds[4][16 * 32];
  bf16_t* myp = plds[wv];  // per-wave slab: no cross-wave sync needed

  short8 qf[4];
  {
    const bf16_t* qp = Qr + (size_t)(q_base + l16) * 2048 + h * 128 + quad * 8;
#pragma unroll
    for (int kc = 0; kc < 4; ++kc) qf[kc] = *(const short8*)(qp + kc * 32);
  }

  const f32x4 zf = {0.f, 0.f, 0.f, 0.f};
  f32x4 o[8];
#pragma unroll
  for (int di = 0; di < 8; ++di) o[di] = zf;
  float m_r[4] = {-1e30f, -1e30f, -1e30f, -1e30f};
  float l_r[4] = {0.f, 0.f, 0.f, 0.f};

  const int kend = q_base + 16;  // causal: k positions [0, q_base+16)
  for (int k0 = 0; k0 < kend; k0 += 32) {
    // S tile 16x32 = two 16x16 MFMA tiles; B-frag = K rows (n=lane&15=kpos)
    f32x4 sacc[2];
    sacc[0] = zf; sacc[1] = zf;
#pragma unroll
    for (int sub = 0; sub < 2; ++sub) {
      int krow = k0 + sub * 16 + l16;  // provably <= 2047
      const bf16_t* kp = Kr + (size_t)krow * 512 + hkv * 128 + quad * 8;
#pragma unroll
      for (int kc = 0; kc < 4; ++kc) {
        short8 kf = *(const short8*)(kp + kc * 32);
        sacc[sub] = __builtin_amdgcn_mfma_f32_16x16x32_bf16(qf[kc], kf, sacc[sub], 0, 0, 0);
      }
    }
    // online softmax per accumulator row (row = quad*4+r, col = lane&15)
    float alpha[4];
#pragma unroll
    for (int r = 0; r < 4; ++r) {
      int qpos = q_base + quad * 4 + r;
      int kp0 = k0 + l16, kp1 = k0 + 16 + l16;
      bool v0 = kp0 <= qpos, v1 = kp1 <= qpos;
      float s0 = v0 ? sacc[0][r] : -1e30f;
      float s1 = v1 ? sacc[1][r] : -1e30f;
      float mx = fmaxf(s0, s1);
#pragma unroll
      for (int d = 1; d < 16; d <<= 1) mx = fmaxf(mx, __shfl_xor(mx, d));
      float mnew = fmaxf(m_r[r], mx);
      float al = __expf(m_r[r] - mnew);
      float p0 = v0 ? __expf(s0 - mnew) : 0.f;  // explicit select: NaN-safe
      float p1 = v1 ? __expf(s1 - mnew) : 0.f;
      float ps = p0 + p1;
#pragma unroll
      for (int d = 1; d < 16; d <<= 1) ps += __shfl_xor(ps, d);
      l_r[r] = l_r[r] * al + ps;
      m_r[r] = mnew;
      alpha[r] = al;
      myp[(quad * 4 + r) * 32 + l16] = f2bf(p0);
      myp[(quad * 4 + r) * 32 + 16 + l16] = f2bf(p1);
    }
#pragma unroll
    for (int di = 0; di < 8; ++di) {
      o[di][0] *= alpha[0]; o[di][1] *= alpha[1];
      o[di][2] *= alpha[2]; o[di][3] *= alpha[3];
    }
    // C-layout -> A-layout round trip through this wave's LDS slab
    __asm__ volatile("s_waitcnt lgkmcnt(0)" ::: "memory");
    short8 pf = *(const short8*)(&myp[l16 * 32 + quad * 8]);
    // PV: B-frag = Vt[d][s] contiguous; V rows provably <= 2047
#pragma unroll
    for (int di = 0; di < 8; ++di) {
      const bf16_t* vp = Vt + (size_t)(hkv * 128 + di * 16 + l16) * 2048 + k0 + quad * 8;
      short8 vfr = *(const short8*)vp;
      o[di] = __builtin_amdgcn_mfma_f32_16x16x32_bf16(pf, vfr, o[di], 0, 0, 0);
    }
  }

  // epilogue: normalize and store bf16 (rows always have >=1 valid col)
  float inv[4];
#pragma unroll
  for (int r = 0; r < 4; ++r) inv[r] = 1.0f / l_r[r];
#pragma unroll
  for (int di = 0; di < 8; ++di) {
#pragma unroll
    for (int r = 0; r < 4; ++r) {
      size_t row = q_base + quad * 4 + r;
      size_t col = h * 128 + di * 16 + l16;
      Oo[row * 2048 + col] = f2bf(o[di][r] * inv[r]);
    }
  }
}

// ---------------- launch ------------------------------------------------------
extern "C" void kernel_launch(void* const* d_in, const int* in_sizes, int n_in,
                              void* d_out, int out_size, void* d_ws, size_t ws_size,
                              hipStream_t stream) {
  (void)in_sizes; (void)n_in; (void)out_size; (void)ws_size;
  const float* query = (const float*)d_in[0];
  const float* key = (const float*)d_in[1];
  const float* value = (const float*)d_in[2];
  const float* Wq = (const float*)d_in[3];
  const float* bq = (const float*)d_in[4];
  const float* Wk = (const float*)d_in[5];
  const float* bk = (const float*)d_in[6];
  const float* Wv = (const float*)d_in[7];
  const float* bv = (const float*)d_in[8];
  const float* Wo = (const float*)d_in[9];
  const float* bo = (const float*)d_in[10];
  float* out = (float*)d_out;

  char* ws = (char*)d_ws;
  const size_t MB = 1024 * 1024;
  bf16_t* qb  = (bf16_t*)(ws + 0 * MB);    // 8 MB  query bf16
  bf16_t* kb  = (bf16_t*)(ws + 8 * MB);    // 8 MB  key bf16
  bf16_t* vb  = (bf16_t*)(ws + 16 * MB);   // 8 MB  value bf16
  bf16_t* wqb = (bf16_t*)(ws + 24 * MB);   // 8 MB
  bf16_t* wkb = (bf16_t*)(ws + 32 * MB);   // 2 MB
  bf16_t* wvb = (bf16_t*)(ws + 34 * MB);   // 2 MB
  bf16_t* wob = (bf16_t*)(ws + 36 * MB);   // 8 MB
  float*  Qf  = (float*)(ws + 44 * MB);    // 16 MB q-proj fp32
  float*  Kf  = (float*)(ws + 60 * MB);    // 4 MB  k-proj fp32
  bf16_t* Qr  = (bf16_t*)(ws + 64 * MB);   // 8 MB  roped+scaled Q bf16
  bf16_t* Kr  = (bf16_t*)(ws + 72 * MB);   // 2 MB  roped K bf16
  bf16_t* Vt  = (bf16_t*)(ws + 74 * MB);   // 2 MB  V^T bf16 (512 x 2048)
  bf16_t* Ob  = (bf16_t*)(ws + 44 * MB);   // 8 MB  attn out bf16 (reuses Qf)

  convert_f32_bf16<<<4096, 256, 0, stream>>>(query, qb, 1048576);
  convert_f32_bf16<<<4096, 256, 0, stream>>>(key, kb, 1048576);
  convert_f32_bf16<<<4096, 256, 0, stream>>>(value, vb, 1048576);
  convert_f32_bf16<<<4096, 256, 0, stream>>>(Wq, wqb, 1048576);
  convert_f32_bf16<<<1024, 256, 0, stream>>>(Wk, wkb, 262144);
  convert_f32_bf16<<<1024, 256, 0, stream>>>(Wv, wvb, 262144);
  convert_f32_bf16<<<4096, 256, 0, stream>>>(Wo, wob, 1048576);

  gemm_nt<0><<<dim3(16, 16), 256, 0, stream>>>(qb, wqb, bq, Qf, 2048, 2048, 2048);
  gemm_nt<0><<<dim3(4, 16), 256, 0, stream>>>(kb, wkb, bk, Kf, 2048, 512, 2048);
  gemm_nt<2><<<dim3(4, 16), 256, 0, stream>>>(vb, wvb, bv, Vt, 2048, 512, 2048);

  rope_qk<<<10240, 256, 0, stream>>>(Qf, Kf, Qr, Kr);

  attn_fwd<<<dim3(16, 32), 256, 0, stream>>>(Qr, Kr, Vt, Ob);

  gemm_nt<0><<<dim3(16, 16), 256, 0, stream>>>(Ob, wob, bo, out, 2048, 2048, 2048);
}

// Round 2
// 468.693 us; speedup vs baseline: 1.2890x; 1.2890x over previous
//
#include <hip/hip_runtime.h>
#include <stdint.h>

typedef __attribute__((ext_vector_type(8))) short short8;   // 8 x bf16 (4 VGPRs)
typedef __attribute__((ext_vector_type(4))) float f32x4;
typedef __attribute__((ext_vector_type(4))) unsigned short u16x4;
typedef unsigned short bf16_t;

__device__ __forceinline__ bf16_t f2bf(float f) {
  union { float f; uint32_t u; } x; x.f = f;
  uint32_t r = x.u + 0x7fffu + ((x.u >> 16) & 1u);   // RNE
  return (bf16_t)(r >> 16);
}

// async global->LDS 16B (direct-to-LDS DMA; LDS dest must be base + lane*16)
__device__ __forceinline__ void ld_g2l_16(const bf16_t* g, bf16_t* l) {
  __builtin_amdgcn_global_load_lds(
      (const __attribute__((address_space(1))) void*)g,
      (__attribute__((address_space(3))) void*)l, 16, 0, 0);
}

// ---------------- fused fp32 -> bf16 convert for all 7 tensors ----------------
// 5 big tensors (1048576 f32x4-groups each) then Wk, Wv (262144 each)
__global__ void convert_all(const float* __restrict__ s0, const float* __restrict__ s1,
                            const float* __restrict__ s2, const float* __restrict__ s3,
                            const float* __restrict__ s4, const float* __restrict__ s5,
                            const float* __restrict__ s6,
                            bf16_t* __restrict__ d0, bf16_t* __restrict__ d1,
                            bf16_t* __restrict__ d2, bf16_t* __restrict__ d3,
                            bf16_t* __restrict__ d4, bf16_t* __restrict__ d5,
                            bf16_t* __restrict__ d6) {
  int i = blockIdx.x * 256 + threadIdx.x;
  const float* src; bf16_t* dst; int off;
  if (i < 5 * 1048576) {
    int t = i >> 20; off = i & 1048575;
    if (t == 0)      { src = s0; dst = d0; }
    else if (t == 1) { src = s1; dst = d1; }
    else if (t == 2) { src = s2; dst = d2; }
    else if (t == 3) { src = s3; dst = d3; }
    else             { src = s4; dst = d4; }
  } else {
    int j = i - 5 * 1048576;
    if (j < 262144) { src = s5; dst = d5; off = j; }
    else            { src = s6; dst = d6; off = j - 262144; }
  }
  f32x4 v = *(const f32x4*)(src + (size_t)off * 4);
  u16x4 o;
  o[0] = f2bf(v[0]); o[1] = f2bf(v[1]); o[2] = f2bf(v[2]); o[3] = f2bf(v[3]);
  *(u16x4*)(dst + (size_t)off * 4) = o;
}

// ---------------- shared NT GEMM core: C[M,N]=A[M,K]*B[N,K]^T + bias[N] -------
// 128x128 tile, 256 threads, BK=32, global_load_lds width-16 staging (m97).
// mode 0: fp32 out[m*N+n];  mode 2: bf16 out[n*Mout+m] (transposed)
__device__ __forceinline__ void gemm_core(
    bf16_t* __restrict__ As, bf16_t* __restrict__ Bs,
    const bf16_t* __restrict__ A, const bf16_t* __restrict__ Bm,
    const float* __restrict__ bias, void* __restrict__ Cout,
    int N, int K, int m0, int n0, int mode, int Mout) {
  const int tid = threadIdx.x;
  const int lane = tid & 63, quad = lane >> 4, l16 = lane & 15;
  const int wv = tid >> 6;
  const int m_off = (wv & 1) * 64, n_off = (wv >> 1) * 64;
  const int c0 = tid, c1 = tid + 256;
  const int r0 = c0 >> 2, col0 = (c0 & 3) * 8;
  const int r1 = c1 >> 2, col1 = (c1 & 3) * 8;

  f32x4 acc[4][4];
  const f32x4 zf = {0.f, 0.f, 0.f, 0.f};
#pragma unroll
  for (int mi = 0; mi < 4; ++mi)
#pragma unroll
    for (int ni = 0; ni < 4; ++ni) acc[mi][ni] = zf;

  const bf16_t* Ap0 = A + (size_t)(m0 + r0) * K + col0;
  const bf16_t* Ap1 = A + (size_t)(m0 + r1) * K + col1;
  const bf16_t* Bp0 = Bm + (size_t)(n0 + r0) * K + col0;
  const bf16_t* Bp1 = Bm + (size_t)(n0 + r1) * K + col1;
  bf16_t* lA0 = As + c0 * 8;  bf16_t* lA1 = As + c1 * 8;
  bf16_t* lB0 = Bs + c0 * 8;  bf16_t* lB1 = Bs + c1 * 8;

  for (int k0 = 0; k0 < K; k0 += 32) {
    ld_g2l_16(Ap0 + k0, lA0);
    ld_g2l_16(Ap1 + k0, lA1);
    ld_g2l_16(Bp0 + k0, lB0);
    ld_g2l_16(Bp1 + k0, lB1);
    __syncthreads();
    short8 af[4], bf[4];
#pragma unroll
    for (int mi = 0; mi < 4; ++mi)
      af[mi] = *(const short8*)(&As[(m_off + mi * 16 + l16) * 32 + quad * 8]);
#pragma unroll
    for (int ni = 0; ni < 4; ++ni)
      bf[ni] = *(const short8*)(&Bs[(n_off + ni * 16 + l16) * 32 + quad * 8]);
#pragma unroll
    for (int mi = 0; mi < 4; ++mi)
#pragma unroll
      for (int ni = 0; ni < 4; ++ni)
        acc[mi][ni] = __builtin_amdgcn_mfma_f32_16x16x32_bf16(
            af[mi], bf[ni], acc[mi][ni], 0, 0, 0);
    __syncthreads();
  }

  // C/D layout: col = lane&15, row = quad*4 + reg
#pragma unroll
  for (int mi = 0; mi < 4; ++mi) {
#pragma unroll
    for (int ni = 0; ni < 4; ++ni) {
      int n = n0 + n_off + ni * 16 + l16;
      int mbase = m0 + m_off + mi * 16 + quad * 4;
      float bv = bias[n];
#pragma unroll
      for (int r = 0; r < 4; ++r) {
        float v = acc[mi][ni][r] + bv;
        int m = mbase + r;
        if (mode == 0) ((float*)Cout)[(size_t)m * N + n] = v;
        else           ((bf16_t*)Cout)[(size_t)n * Mout + m] = f2bf(v);
      }
    }
  }
}

// fused Q/K/V projections: bx<16 -> Q, 16..19 -> K, 20..23 -> V(transposed out)
__global__ __launch_bounds__(256) void gemm_qkv(
    const bf16_t* __restrict__ qb, const bf16_t* __restrict__ kb,
    const bf16_t* __restrict__ vb, const bf16_t* __restrict__ wqb,
    const bf16_t* __restrict__ wkb, const bf16_t* __restrict__ wvb,
    const float* __restrict__ bq, const float* __restrict__ bk,
    const float* __restrict__ bv, float* __restrict__ Qf,
    float* __restrict__ Kf, bf16_t* __restrict__ Vt) {
  __shared__ __align__(16) bf16_t As[128 * 32];
  __shared__ __align__(16) bf16_t Bs[128 * 32];
  int bx = blockIdx.x, m0 = blockIdx.y * 128;
  if (bx < 16)
    gemm_core(As, Bs, qb, wqb, bq, Qf, 2048, 2048, m0, bx * 128, 0, 0);
  else if (bx < 20)
    gemm_core(As, Bs, kb, wkb, bk, Kf, 512, 2048, m0, (bx - 16) * 128, 0, 0);
  else
    gemm_core(As, Bs, vb, wvb, bv, Vt, 512, 2048, m0, (bx - 20) * 128, 2, 2048);
}

__global__ __launch_bounds__(256) void gemm_o(
    const bf16_t* __restrict__ Ob, const bf16_t* __restrict__ wob,
    const float* __restrict__ bo, float* __restrict__ out) {
  __shared__ __align__(16) bf16_t As[128 * 32];
  __shared__ __align__(16) bf16_t Bs[128 * 32];
  gemm_core(As, Bs, Ob, wob, bo, out, 2048, 2048,
            blockIdx.y * 128, blockIdx.x * 128, 0, 0);
}

// ---------------- RoPE + bf16 cast (Q pre-scaled by 1/sqrt(128)) --------------
__global__ void rope_qk(const float* __restrict__ Qf, const float* __restrict__ Kf,
                        bf16_t* __restrict__ Qr, bf16_t* __restrict__ Kr) {
  int idx = blockIdx.x * 256 + threadIdx.x;
  int i = idx & 63;
  int rest = idx >> 6;
  int head = rest % 20;
  int s = rest / 20;
  float inv_freq = powf(10000.0f, -(float)i * (1.0f / 64.0f));
  float ang = (float)s * inv_freq;
  float c = cosf(ang), sn = sinf(ang);
  if (head < 16) {
    const float scale = 0.08838834764831845f;  // 1/sqrt(128)
    size_t base = (size_t)s * 2048 + head * 128 + i;
    float x1 = Qf[base], x2 = Qf[base + 64];
    Qr[base] = f2bf((x1 * c - x2 * sn) * scale);
    Qr[base + 64] = f2bf((x2 * c + x1 * sn) * scale);
  } else {
    size_t base = (size_t)s * 512 + (head - 16) * 128 + i;
    float x1 = Kf[base], x2 = Kf[base + 64];
    Kr[base] = f2bf(x1 * c - x2 * sn);
    Kr[base + 64] = f2bf(x2 * c + x1 * sn);
  }
}

// ---------------- causal GQA flash attention, A-layout softmax ----------------
// grid (32 qt reversed, 16 heads); 4 waves/block, wave owns 16 q rows, k-step 64.
// Per-tile: QK MFMA (C-layout) -> mask -> fp32 S to LDS -> read A-layout
// (row=l16, k=quad*8+j) -> in-lane reduce + 2 shfl_xor (^16,^32) -> P frag in
// registers -> PV MFMA. alpha/l broadcast to C-layout rows via __shfl.
__global__ __launch_bounds__(256) void attn_fwd(
    const bf16_t* __restrict__ Qr, const bf16_t* __restrict__ Kr,
    const bf16_t* __restrict__ Vt, bf16_t* __restrict__ Oo) {
  const int h = blockIdx.y;
  const int qt = 31 - blockIdx.x;   // heavy blocks dispatch first
  const int tid = threadIdx.x;
  const int wv = tid >> 6, lane = tid & 63, quad = lane >> 4, l16 = lane & 15;
  const int q_base = qt * 64 + wv * 16;
  const int hkv = h >> 2;

  __shared__ __align__(16) float Sb[4][16 * 66];  // stride 66: conflict-tamed
  float* mys = Sb[wv];

  short8 qf[4];
  {
    const bf16_t* qp = Qr + (size_t)(q_base + l16) * 2048 + h * 128 + quad * 8;
#pragma unroll
    for (int kc = 0; kc < 4; ++kc) qf[kc] = *(const short8*)(qp + kc * 32);
  }

  const f32x4 zf = {0.f, 0.f, 0.f, 0.f};
  f32x4 o[8];
#pragma unroll
  for (int di = 0; di < 8; ++di) o[di] = zf;
  float m_a = -1e30f, l_a = 0.f;   // state for q-row l16 (replicated over quads)

  const int kend = q_base + 16;
  for (int k0 = 0; k0 < kend; k0 += 64) {
    // V fragments early (independent of softmax chain)
    short8 vf0[8], vf1[8];
    {
      const bf16_t* vpb = Vt + (size_t)(hkv * 128 + l16) * 2048 + k0 + quad * 8;
#pragma unroll
      for (int di = 0; di < 8; ++di) {
        const bf16_t* vp = vpb + (size_t)(di * 16) * 2048;
        vf0[di] = *(const short8*)vp;
        vf1[di] = *(const short8*)(vp + 32);
      }
    }
    // QK^T: 16x64 scores, C-layout rows quad*4+r, cols sub*16+l16
    f32x4 sacc[4];
#pragma unroll
    for (int sub = 0; sub < 4; ++sub) sacc[sub] = zf;
#pragma unroll
    for (int sub = 0; sub < 4; ++sub) {
      const bf16_t* kp = Kr + (size_t)(k0 + sub * 16 + l16) * 512 + hkv * 128 + quad * 8;
#pragma unroll
      for (int kc = 0; kc < 4; ++kc) {
        short8 kf = *(const short8*)(kp + kc * 32);
        sacc[sub] = __builtin_amdgcn_mfma_f32_16x16x32_bf16(qf[kc], kf, sacc[sub], 0, 0, 0);
      }
    }
    if (k0 + 63 > q_base) {  // diagonal tile: causal mask (wave-uniform branch)
#pragma unroll
      for (int sub = 0; sub < 4; ++sub)
#pragma unroll
        for (int r = 0; r < 4; ++r) {
          int qpos = q_base + quad * 4 + r;
          int col = k0 + sub * 16 + l16;
          if (col > qpos) sacc[sub][r] = -1e30f;
        }
    }
    // C-layout -> LDS -> A-layout
#pragma unroll
    for (int sub = 0; sub < 4; ++sub)
#pragma unroll
      for (int r = 0; r < 4; ++r)
        mys[(quad * 4 + r) * 66 + sub * 16 + l16] = sacc[sub][r];
    __asm__ volatile("s_waitcnt lgkmcnt(0)" ::: "memory");
    float s[16];
    {
      const float* rp = mys + l16 * 66 + quad * 8;
#pragma unroll
      for (int j = 0; j < 8; ++j) { s[j] = rp[j]; s[8 + j] = rp[32 + j]; }
    }
    // online softmax for row l16: in-lane + 2 cross-quad shuffles
    float mx = s[0];
#pragma unroll
    for (int j = 1; j < 16; ++j) mx = fmaxf(mx, s[j]);
    mx = fmaxf(mx, __shfl_xor(mx, 16));
    mx = fmaxf(mx, __shfl_xor(mx, 32));
    float mnew = fmaxf(m_a, mx);
    float alpha = __expf(m_a - mnew);
    m_a = mnew;
    float p[16], rs = 0.f;
#pragma unroll
    for (int j = 0; j < 16; ++j) { p[j] = __expf(s[j] - mnew); rs += p[j]; }
    rs += __shfl_xor(rs, 16);
    rs += __shfl_xor(rs, 32);
    l_a = l_a * alpha + rs;
    short8 pf0, pf1;
#pragma unroll
    for (int j = 0; j < 8; ++j) {
      pf0[j] = (short)f2bf(p[j]);
      pf1[j] = (short)f2bf(p[8 + j]);
    }
    // alpha to C-layout rows (quad*4+r) and rescale O
    float ac[4];
#pragma unroll
    for (int r = 0; r < 4; ++r) ac[r] = __shfl(alpha, quad * 4 + r, 64);
#pragma unroll
    for (int di = 0; di < 8; ++di) {
      o[di][0] *= ac[0]; o[di][1] *= ac[1]; o[di][2] *= ac[2]; o[di][3] *= ac[3];
    }
    // PV accumulate
#pragma unroll
    for (int di = 0; di < 8; ++di) {
      o[di] = __builtin_amdgcn_mfma_f32_16x16x32_bf16(pf0, vf0[di], o[di], 0, 0, 0);
      o[di] = __builtin_amdgcn_mfma_f32_16x16x32_bf16(pf1, vf1[di], o[di], 0, 0, 0);
    }
  }

  float linv[4];
#pragma unroll
  for (int r = 0; r < 4; ++r) linv[r] = 1.0f / __shfl(l_a, quad * 4 + r, 64);
#pragma unroll
  for (int di = 0; di < 8; ++di)
#pragma unroll
    for (int r = 0; r < 4; ++r) {
      size_t row = q_base + quad * 4 + r;
      size_t col = h * 128 + di * 16 + l16;
      Oo[row * 2048 + col] = f2bf(o[di][r] * linv[r]);
    }
}

// ---------------- launch ------------------------------------------------------
extern "C" void kernel_launch(void* const* d_in, const int* in_sizes, int n_in,
                              void* d_out, int out_size, void* d_ws, size_t ws_size,
                              hipStream_t stream) {
  (void)in_sizes; (void)n_in; (void)out_size; (void)ws_size;
  const float* query = (const float*)d_in[0];
  const float* key = (const float*)d_in[1];
  const float* value = (const float*)d_in[2];
  const float* Wq = (const float*)d_in[3];
  const float* bq = (const float*)d_in[4];
  const float* Wk = (const float*)d_in[5];
  const float* bk = (const float*)d_in[6];
  const float* Wv = (const float*)d_in[7];
  const float* bv = (const float*)d_in[8];
  const float* Wo = (const float*)d_in[9];
  const float* bo = (const float*)d_in[10];
  float* out = (float*)d_out;

  char* ws = (char*)d_ws;
  const size_t MB = 1024 * 1024;
  bf16_t* qb  = (bf16_t*)(ws + 0 * MB);
  bf16_t* kb  = (bf16_t*)(ws + 8 * MB);
  bf16_t* vb  = (bf16_t*)(ws + 16 * MB);
  bf16_t* wqb = (bf16_t*)(ws + 24 * MB);
  bf16_t* wkb = (bf16_t*)(ws + 32 * MB);
  bf16_t* wvb = (bf16_t*)(ws + 34 * MB);
  bf16_t* wob = (bf16_t*)(ws + 36 * MB);
  float*  Qf  = (float*)(ws + 44 * MB);    // 16 MB
  float*  Kf  = (float*)(ws + 60 * MB);    // 4 MB
  bf16_t* Qr  = (bf16_t*)(ws + 64 * MB);   // 8 MB
  bf16_t* Kr  = (bf16_t*)(ws + 72 * MB);   // 2 MB
  bf16_t* Vt  = (bf16_t*)(ws + 74 * MB);   // 2 MB (512 x 2048)
  bf16_t* Ob  = (bf16_t*)(ws + 44 * MB);   // 8 MB (reuses Qf)

  convert_all<<<22528, 256, 0, stream>>>(query, key, value, Wq, Wo, Wk, Wv,
                                         qb, kb, vb, wqb, wob, wkb, wvb);
  gemm_qkv<<<dim3(24, 16), 256, 0, stream>>>(qb, kb, vb, wqb, wkb, wvb,
                                             bq, bk, bv, Qf, Kf, Vt);
  rope_qk<<<10240, 256, 0, stream>>>(Qf, Kf, Qr, Kr);
  attn_fwd<<<dim3(32, 16), 256, 0, stream>>>(Qr, Kr, Vt, Ob);
  gemm_o<<<dim3(16, 16), 256, 0, stream>>>(Ob, wob, bo, out);
}